// Round 4
// baseline (699.147 us; speedup 1.0000x reference)
//
#include <hip/hip_runtime.h>

// VQ-VAE Vector Quantizer: N=65536 rows, K=4096 codes, D=64, fp32.
// R6: restructure the e-feed from SMEM (s_load + out-of-order lgkmcnt(0) hard
// drain each iteration) to LDS broadcast (ds_read_b128, in-order lgkmcnt ->
// compiler emits fine-grained partial waits). e-tile of 64 codes (16KB) staged
// per block; reads are wave-uniform => bank-conflict-free broadcast. All FMAs
// become v_fmac v,v,v. z row is loaded ONCE via volatile scalar loads (cannot
// be sunk/rematerialized into the k-loop - the VGPR_Count=40 evidence across
// R0-R5 shows the scheduler re-loads z in-loop when targeting 8 waves/EU) and
// the occupancy target is pinned to 4 waves/EU (VGPR budget 128, need ~95).
// FMA sequence per (row,code) is bit-identical to the R2/R3 passing kernels
// (quad-split partials by d mod 4, ascending d, (s0+s1)+(s2+s3), then
// dist = (z2 + e2[k]) - 2*dot, strict < first-index tie-break) => identical
// indices, absmax 0 by construction.
//
// out layout (float): [0,N*D) z_q_st | [ND] vq | [ND+1] cb | [ND+2] cm |
//                     [ND+3, ND+3+N) indices | [ND+3+N] perplexity | [ND+4+N] active

constexpr int N = 65536;
constexpr int K = 4096;
constexpr int D = 64;
constexpr int S = 8;       // K-split: 8 slices
constexpr int KS = K / S;  // 512 codes per slice
constexpr int KT = 64;     // codes per LDS tile (16 KB)

__global__ __launch_bounds__(256) void prep_kernel(const float* __restrict__ emb,
                                                   float* __restrict__ e2,
                                                   int* __restrict__ counts,
                                                   float* __restrict__ loss) {
  int k = blockIdx.x * 256 + threadIdx.x;
  if (k < K) {
    const float4* ep = (const float4*)(emb + (size_t)k * D);
    float s0 = 0.f, s1 = 0.f, s2 = 0.f, s3 = 0.f;
#pragma unroll
    for (int i = 0; i < 16; ++i) {
      float4 e = ep[i];
      s0 = fmaf(e.x, e.x, s0);
      s1 = fmaf(e.y, e.y, s1);
      s2 = fmaf(e.z, e.z, s2);
      s3 = fmaf(e.w, e.w, s3);
    }
    e2[k] = (s0 + s1) + (s2 + s3);
    counts[k] = 0;
  }
  if (blockIdx.x == 0 && threadIdx.x == 0) *loss = 0.0f;
}

// Scan one K-slice for 256 rows per block. grid = (N/256, S).
// LDS: 64-code e-tile (16KB) + e2 tile. 4 waves/EU occupancy target.
__global__ __launch_bounds__(256, 4)
__attribute__((amdgpu_waves_per_eu(4)))
void vq_scan(const float* __restrict__ z,
             const float* __restrict__ emb,
             const float* __restrict__ e2,
             float* __restrict__ pbest,
             int* __restrict__ pidx) {
  __shared__ float4 e4[KT * 16];  // [code][d/4] : 16 KB
  __shared__ float e2s[KT];

  const int tid = threadIdx.x;
  const int n = blockIdx.x * 256 + tid;
  const int s = blockIdx.y;
  const int k0 = s * KS;

  // This lane's z row, loaded exactly once (volatile: not sinkable/remat-able).
  float zf[64];
  {
    const volatile float* zp = z + (size_t)n * D;
#pragma unroll
    for (int d = 0; d < 64; ++d) zf[d] = zp[d];
  }

  // z2, same instruction sequence as R2 (quad-split by d mod 4, ascending d).
  float z2;
  {
    float s0 = 0.f, s1 = 0.f, s2 = 0.f, s3 = 0.f;
#pragma unroll
    for (int i = 0; i < 16; ++i) {
      s0 = fmaf(zf[4 * i + 0], zf[4 * i + 0], s0);
      s1 = fmaf(zf[4 * i + 1], zf[4 * i + 1], s1);
      s2 = fmaf(zf[4 * i + 2], zf[4 * i + 2], s2);
      s3 = fmaf(zf[4 * i + 3], zf[4 * i + 3], s3);
    }
    z2 = (s0 + s1) + (s2 + s3);
  }

  float best = 3.4e38f;
  int bidx = k0;

  for (int t = 0; t < KS / KT; ++t) {
    const int kt0 = k0 + t * KT;
    // Stage 64 codes (16 KB) into LDS, coalesced: 1024 float4s / 256 threads.
    const float4* src = (const float4*)(emb + (size_t)kt0 * D);
    __syncthreads();  // previous tile fully consumed
#pragma unroll
    for (int p = 0; p < 4; ++p) e4[tid + p * 256] = src[tid + p * 256];
    if (tid < KT) e2s[tid] = e2[kt0 + tid];
    __syncthreads();

    for (int kk = 0; kk < KT; ++kk) {
      const float4* ek = &e4[kk * 16];  // wave-uniform address -> broadcast
      float s0 = 0.f, s1 = 0.f, s2 = 0.f, s3 = 0.f;
#pragma unroll
      for (int c = 0; c < 4; ++c) {
#pragma unroll
        for (int j = 0; j < 4; ++j) {
          // d = 16*c + 4*j + {0,1,2,3}; partial sN takes d%4==N, ascending d
          float4 e = ek[c * 4 + j];
          s0 = fmaf(zf[16 * c + 4 * j + 0], e.x, s0);
          s1 = fmaf(zf[16 * c + 4 * j + 1], e.y, s1);
          s2 = fmaf(zf[16 * c + 4 * j + 2], e.z, s2);
          s3 = fmaf(zf[16 * c + 4 * j + 3], e.w, s3);
        }
      }
      float dot = (s0 + s1) + (s2 + s3);
      float dist = (z2 + e2s[kk]) - 2.0f * dot;  // reference fp32 rounding replicated
      if (dist < best) { best = dist; bidx = kt0 + kk; }  // strict <: first index
    }
  }

  pbest[(size_t)s * N + n] = best;
  pidx[(size_t)s * N + n] = bidx;
}

// Combine slices (ascending s = ascending k => first-index tie-break preserved),
// then gather/losses/counts/index write.
__global__ __launch_bounds__(256) void vq_epilogue(const float* __restrict__ z,
                                                   const float* __restrict__ emb,
                                                   const float* __restrict__ pbest,
                                                   const int* __restrict__ pidx,
                                                   float* __restrict__ out,
                                                   int* __restrict__ counts,
                                                   float* __restrict__ loss) {
  __shared__ float red[4];
  const int tid = threadIdx.x;
  const int n = blockIdx.x * 256 + tid;

  float best = pbest[n];
  int bidx = pidx[n];
#pragma unroll
  for (int s = 1; s < S; ++s) {
    float d = pbest[(size_t)s * N + n];
    if (d < best) { best = d; bidx = pidx[(size_t)s * N + n]; }
  }

  out[(size_t)N * D + 3 + n] = (float)bidx;
  atomicAdd(&counts[bidx], 1);

  const float4* zp = (const float4*)(z + (size_t)n * D);
  const float4* qp = (const float4*)(emb + (size_t)bidx * D);
  float4* op = (float4*)(out + (size_t)n * D);
  float lsum = 0.f;
#pragma unroll
  for (int i = 0; i < 16; ++i) {
    float4 q = qp[i];
    float4 zz = zp[i];
    float dx = q.x - zz.x, dy = q.y - zz.y, dz = q.z - zz.z, dw = q.w - zz.w;
    lsum = fmaf(dx, dx, lsum);
    lsum = fmaf(dy, dy, lsum);
    lsum = fmaf(dz, dz, lsum);
    lsum = fmaf(dw, dw, lsum);
    // z_q_st = z + (z_q - z), replicated op-for-op
    float4 r;
    r.x = zz.x + dx; r.y = zz.y + dy; r.z = zz.z + dz; r.w = zz.w + dw;
    op[i] = r;
  }

#pragma unroll
  for (int off = 32; off > 0; off >>= 1) lsum += __shfl_down(lsum, off);
  if ((tid & 63) == 0) red[tid >> 6] = lsum;
  __syncthreads();
  if (tid == 0) atomicAdd(loss, (red[0] + red[1]) + (red[2] + red[3]));
}

__global__ __launch_bounds__(256) void finalize_kernel(const int* __restrict__ counts,
                                                       const float* __restrict__ loss,
                                                       float* __restrict__ out) {
  const int tid = threadIdx.x;
  double ent = 0.0;
  int active = 0;
  for (int k = tid; k < K; k += 256) {
    int c = counts[k];
    float p = (float)c / 65536.0f;
    if (c > 0) active++;
    ent += (double)(p * logf(p + 1e-10f));
  }
#pragma unroll
  for (int off = 32; off > 0; off >>= 1) {
    ent += __shfl_down(ent, off);
    active += __shfl_down(active, off);
  }
  __shared__ double ered[4];
  __shared__ int ared[4];
  if ((tid & 63) == 0) { ered[tid >> 6] = ent; ared[tid >> 6] = active; }
  __syncthreads();
  if (tid == 0) {
    double e = (ered[0] + ered[1]) + (ered[2] + ered[3]);
    int a = (ared[0] + ared[1]) + (ared[2] + ared[3]);
    float mean = *loss / (float)((size_t)N * D);
    float cb = mean;
    float cm = mean;
    float vq = cb + 0.25f * cm;
    size_t base = (size_t)N * D;
    out[base + 0] = vq;
    out[base + 1] = cb;
    out[base + 2] = cm;
    out[base + 3 + N] = (float)exp(-e);
    out[base + 4 + N] = (float)a;
  }
}

extern "C" void kernel_launch(void* const* d_in, const int* in_sizes, int n_in,
                              void* d_out, int out_size, void* d_ws, size_t ws_size,
                              hipStream_t stream) {
  const float* z = (const float*)d_in[0];
  const float* emb = (const float*)d_in[1];
  float* out = (float*)d_out;

  char* w = (char*)d_ws;
  float* e2 = (float*)w;                         w += (size_t)K * sizeof(float);
  int* counts = (int*)w;                         w += (size_t)K * sizeof(int);
  float* loss = (float*)w;                       w += 256;  // keep alignment
  float* pbest = (float*)w;                      w += (size_t)S * N * sizeof(float);
  int* pidx = (int*)w;

  prep_kernel<<<K / 256, 256, 0, stream>>>(emb, e2, counts, loss);
  vq_scan<<<dim3(N / 256, S), 256, 0, stream>>>(z, emb, e2, pbest, pidx);
  vq_epilogue<<<N / 256, 256, 0, stream>>>(z, emb, pbest, pidx, out, counts, loss);
  finalize_kernel<<<1, 256, 0, stream>>>(counts, loss, out);
}

// Round 5
// 495.397 us; speedup vs baseline: 1.4113x; 1.4113x over previous
//
#include <hip/hip_runtime.h>

// VQ-VAE Vector Quantizer: N=65536 rows, K=4096 codes, D=64, fp32.
// R7: VMEM-broadcast e-feed with float4-granular software pipeline.
// Post-mortem model (R0-R6): z IS register-resident (AGPRs on gfx950 unified
// file; per-iter re-load is arithmetically impossible at 500us). The stall is
// the e-feed: SMEM s_load completes OUT-OF-ORDER -> only lgkmcnt(0) full
// drains are legal -> ~200-300cy L2 stall per code at 4 waves/SIMD = 64% VALU
// (R0). LDS broadcast (R6) is worse: 16 waves/CU re-read the same 16B through
// one DS pipe. Fix: e via per-lane VMEM loads at wave-uniform address (hw
// coalesces to one transaction, broadcast return). VMEM is IN-ORDER ->
// compiler emits fine-grained vmcnt(N) partial waits. rr/qq banks give a
// 16-float4 prefetch distance (code k+1 streams while code k FMAs), WAR deps
// pin legality. All e-bank indices compile-time (full unroll) per rule #20.
// FMA sequence per (row,code) is bit-identical to the R0/R2/R3 passing
// kernels (quad-split partials by d mod 4, ascending d, (s0+s1)+(s2+s3),
// dist = (z2 + e2[k]) - 2*dot, strict < first-index tie-break) => identical
// indices, absmax 0 by construction.
//
// out layout (float): [0,N*D) z_q_st | [ND] vq | [ND+1] cb | [ND+2] cm |
//                     [ND+3, ND+3+N) indices | [ND+3+N] perplexity | [ND+4+N] active

constexpr int N = 65536;
constexpr int K = 4096;
constexpr int D = 64;
constexpr int S = 8;      // K-split: grid = 2048 blocks
constexpr int KS = K / S; // 512 codes per slice

__global__ __launch_bounds__(256) void prep_kernel(const float* __restrict__ emb,
                                                   float* __restrict__ e2,
                                                   int* __restrict__ counts,
                                                   float* __restrict__ loss) {
  int k = blockIdx.x * 256 + threadIdx.x;
  if (k < K) {
    const float4* ep = (const float4*)(emb + (size_t)k * D);
    float s0 = 0.f, s1 = 0.f, s2 = 0.f, s3 = 0.f;
#pragma unroll
    for (int i = 0; i < 16; ++i) {
      float4 e = ep[i];
      s0 = fmaf(e.x, e.x, s0);
      s1 = fmaf(e.y, e.y, s1);
      s2 = fmaf(e.z, e.z, s2);
      s3 = fmaf(e.w, e.w, s3);
    }
    e2[k] = (s0 + s1) + (s2 + s3);
    counts[k] = 0;
  }
  if (blockIdx.x == 0 && threadIdx.x == 0) *loss = 0.0f;
}

// Scan one K-slice for 256 rows per block. grid = (N/256, S). No LDS.
__global__ __launch_bounds__(256) void vq_scan(const float* __restrict__ z,
                                               const float* __restrict__ emb,
                                               const float* __restrict__ e2,
                                               float* __restrict__ pbest,
                                               int* __restrict__ pidx) {
  const int tid = threadIdx.x;
  const int n = blockIdx.x * 256 + tid;
  const int s = blockIdx.y;
  const int k0 = s * KS;

  // This lane's z row (compiler keeps it resident — AGPRs on the unified file).
  float4 zr[16];
  {
    const float4* zp = (const float4*)(z + (size_t)n * D);
#pragma unroll
    for (int i = 0; i < 16; ++i) zr[i] = zp[i];
  }

  // z2, same instruction sequence as R0 (quad-split by d mod 4, ascending d).
  float z2;
  {
    float s0 = 0.f, s1 = 0.f, s2 = 0.f, s3 = 0.f;
#pragma unroll
    for (int i = 0; i < 16; ++i) {
      s0 = fmaf(zr[i].x, zr[i].x, s0);
      s1 = fmaf(zr[i].y, zr[i].y, s1);
      s2 = fmaf(zr[i].z, zr[i].z, s2);
      s3 = fmaf(zr[i].w, zr[i].w, s3);
    }
    z2 = (s0 + s1) + (s2 + s3);
  }

  // Flat float4 stream of this slice's codebook: code k = fp[16k .. 16k+15].
  const float4* fp = (const float4*)(emb + (size_t)k0 * D);
  const float* e2p = e2 + k0;

  // Prologue: preload code 0 into the two banks (f=0..7 -> rr, f=8..15 -> qq).
  float4 rr[8], qq[8];
#pragma unroll
  for (int j = 0; j < 8; ++j) rr[j] = fp[j];
#pragma unroll
  for (int j = 0; j < 8; ++j) qq[j] = fp[8 + j];
  float e2cur = e2p[0];

  float best = 3.4e38f;
  int bidx = k0;

  for (int k = 0; k < KS; ++k) {
    const int kn = (k + 1 < KS) ? (k + 1) : (KS - 1);  // clamped (last prefetch is dead)
    const float4* fn = fp + (size_t)kn * 16;

    float s0 = 0.f, s1 = 0.f, s2 = 0.f, s3 = 0.f;
    // Phase 1: consume rr (f=0..7 of code k), refill with code kn.
#pragma unroll
    for (int j = 0; j < 8; ++j) {
      float4 e = rr[j];
      // d = 4*f + {0,1,2,3}, f=j: partial sN takes d%4==N, ascending d
      s0 = fmaf(zr[j].x, e.x, s0);
      s1 = fmaf(zr[j].y, e.y, s1);
      s2 = fmaf(zr[j].z, e.z, s2);
      s3 = fmaf(zr[j].w, e.w, s3);
      rr[j] = fn[j];  // WAR: legal only after the FMAs above; in flight ~1 code
    }
    float e2n = e2p[kn];
    // Phase 2: consume qq (f=8..15 of code k), refill with code kn.
#pragma unroll
    for (int j = 0; j < 8; ++j) {
      float4 e = qq[j];
      s0 = fmaf(zr[8 + j].x, e.x, s0);
      s1 = fmaf(zr[8 + j].y, e.y, s1);
      s2 = fmaf(zr[8 + j].z, e.z, s2);
      s3 = fmaf(zr[8 + j].w, e.w, s3);
      qq[j] = fn[8 + j];
    }
    float dot = (s0 + s1) + (s2 + s3);
    float dist = (z2 + e2cur) - 2.0f * dot;  // reference fp32 rounding replicated
    if (dist < best) { best = dist; bidx = k0 + k; }  // strict <: first-index in slice
    e2cur = e2n;
  }

  pbest[(size_t)s * N + n] = best;
  pidx[(size_t)s * N + n] = bidx;
}

// Combine slices (ascending s = ascending k => first-index tie-break preserved),
// then gather/losses/counts/index write.
__global__ __launch_bounds__(256) void vq_epilogue(const float* __restrict__ z,
                                                   const float* __restrict__ emb,
                                                   const float* __restrict__ pbest,
                                                   const int* __restrict__ pidx,
                                                   float* __restrict__ out,
                                                   int* __restrict__ counts,
                                                   float* __restrict__ loss) {
  __shared__ float red[4];
  const int tid = threadIdx.x;
  const int n = blockIdx.x * 256 + tid;

  float best = pbest[n];
  int bidx = pidx[n];
#pragma unroll
  for (int s = 1; s < S; ++s) {
    float d = pbest[(size_t)s * N + n];
    if (d < best) { best = d; bidx = pidx[(size_t)s * N + n]; }
  }

  out[(size_t)N * D + 3 + n] = (float)bidx;
  atomicAdd(&counts[bidx], 1);

  const float4* zp = (const float4*)(z + (size_t)n * D);
  const float4* qp = (const float4*)(emb + (size_t)bidx * D);
  float4* op = (float4*)(out + (size_t)n * D);
  float lsum = 0.f;
#pragma unroll
  for (int i = 0; i < 16; ++i) {
    float4 q = qp[i];
    float4 zz = zp[i];
    float dx = q.x - zz.x, dy = q.y - zz.y, dz = q.z - zz.z, dw = q.w - zz.w;
    lsum = fmaf(dx, dx, lsum);
    lsum = fmaf(dy, dy, lsum);
    lsum = fmaf(dz, dz, lsum);
    lsum = fmaf(dw, dw, lsum);
    // z_q_st = z + (z_q - z), replicated op-for-op
    float4 r;
    r.x = zz.x + dx; r.y = zz.y + dy; r.z = zz.z + dz; r.w = zz.w + dw;
    op[i] = r;
  }

#pragma unroll
  for (int off = 32; off > 0; off >>= 1) lsum += __shfl_down(lsum, off);
  if ((tid & 63) == 0) red[tid >> 6] = lsum;
  __syncthreads();
  if (tid == 0) atomicAdd(loss, (red[0] + red[1]) + (red[2] + red[3]));
}

__global__ __launch_bounds__(256) void finalize_kernel(const int* __restrict__ counts,
                                                       const float* __restrict__ loss,
                                                       float* __restrict__ out) {
  const int tid = threadIdx.x;
  double ent = 0.0;
  int active = 0;
  for (int k = tid; k < K; k += 256) {
    int c = counts[k];
    float p = (float)c / 65536.0f;
    if (c > 0) active++;
    ent += (double)(p * logf(p + 1e-10f));
  }
#pragma unroll
  for (int off = 32; off > 0; off >>= 1) {
    ent += __shfl_down(ent, off);
    active += __shfl_down(active, off);
  }
  __shared__ double ered[4];
  __shared__ int ared[4];
  if ((tid & 63) == 0) { ered[tid >> 6] = ent; ared[tid >> 6] = active; }
  __syncthreads();
  if (tid == 0) {
    double e = (ered[0] + ered[1]) + (ered[2] + ered[3]);
    int a = (ared[0] + ared[1]) + (ared[2] + ared[3]);
    float mean = *loss / (float)((size_t)N * D);
    float cb = mean;
    float cm = mean;
    float vq = cb + 0.25f * cm;
    size_t base = (size_t)N * D;
    out[base + 0] = vq;
    out[base + 1] = cb;
    out[base + 2] = cm;
    out[base + 3 + N] = (float)exp(-e);
    out[base + 4 + N] = (float)a;
  }
}

extern "C" void kernel_launch(void* const* d_in, const int* in_sizes, int n_in,
                              void* d_out, int out_size, void* d_ws, size_t ws_size,
                              hipStream_t stream) {
  const float* z = (const float*)d_in[0];
  const float* emb = (const float*)d_in[1];
  float* out = (float*)d_out;

  char* w = (char*)d_ws;
  float* e2 = (float*)w;                         w += (size_t)K * sizeof(float);
  int* counts = (int*)w;                         w += (size_t)K * sizeof(int);
  float* loss = (float*)w;                       w += 256;  // keep alignment
  float* pbest = (float*)w;                      w += (size_t)S * N * sizeof(float);
  int* pidx = (int*)w;

  prep_kernel<<<K / 256, 256, 0, stream>>>(emb, e2, counts, loss);
  vq_scan<<<dim3(N / 256, S), 256, 0, stream>>>(z, emb, e2, pbest, pidx);
  vq_epilogue<<<N / 256, 256, 0, stream>>>(z, emb, pbest, pidx, out, counts, loss);
  finalize_kernel<<<1, 256, 0, stream>>>(counts, loss, out);
}